// Round 16
// baseline (350.650 us; speedup 1.0000x reference)
//
#include <hip/hip_runtime.h>
#include <cstddef>
#include <cstdint>

#define N_     2048
#define H_     32
#define NEGF   (-1.0e30f)
#define LOG2E  1.4426950408889634f
#define C1F    (0.17677669529663687f * 1.4426950408889634f)   // (1/sqrt(32))*log2e
#define DEFER  16.0f
#define NCHUNK 32
#define CLEN   64             // N_/NCHUNK
#define NRTOT  8192           // B*N
#define PREC   20             // u32 per (chunk,row) pacc record: 16 bf16-pair + 4 f32

typedef float v2f __attribute__((ext_vector_type(2)));

__device__ __forceinline__ float exp2_fast(float x) {
    float r;
    asm("v_exp_f32 %0, %1" : "=v"(r) : "v"(x));
    return r;
}

// RNE float -> bf16 (as u16 in low bits)
__device__ __forceinline__ unsigned f2bf(float x) {
    unsigned u = __builtin_bit_cast(unsigned, x);
    return (u + 0x7FFFu + ((u >> 16) & 1u)) >> 16;
}
__device__ __forceinline__ unsigned packbf(v2f v) {
    return f2bf(v.x) | (f2bf(v.y) << 16);
}

// ---------------------------------------------------------------- adj -> bitmask
__global__ __launch_bounds__(256) void k_adjmask(const int* __restrict__ adj,
                                                 unsigned long long* __restrict__ mask) {
    size_t idx = (size_t)blockIdx.x * 256 + threadIdx.x;     // over B*N*N
    unsigned long long m = __ballot(adj[idx] != 0);
    if ((threadIdx.x & 63) == 0) mask[idx >> 6] = m;
}

// ---------------------------------------------------------------- fused h-init + layer-0 qkv
__global__ __launch_bounds__(256) void k_init_qkv(const float* __restrict__ feats,
                                                  const float* __restrict__ W_in,
                                                  const float* __restrict__ Wq,
                                                  const float* __restrict__ Wk,
                                                  const float* __restrict__ Wv,
                                                  float* __restrict__ h,
                                                  float* __restrict__ q,
                                                  float* __restrict__ k,
                                                  float* __restrict__ v) {
    __shared__ float hs[8][33];
    int t = threadIdx.x;
    int rl = t >> 5, c = t & 31;
    int row = blockIdx.x * 8 + rl;
    float f0 = feats[row * 3 + 0], f1 = feats[row * 3 + 1], f2 = feats[row * 3 + 2];
    float hv = f0 * W_in[c] + f1 * W_in[32 + c] + f2 * W_in[64 + c];
    hs[rl][c] = hv;
    h[(row << 5) + c] = hv;
    __syncthreads();
    float aq = 0.f, ak = 0.f, av = 0.f;
#pragma unroll
    for (int d = 0; d < 32; ++d) {
        float hd = hs[rl][d];
        aq += hd * Wq[(d << 5) + c];
        ak += hd * Wk[(d << 5) + c];
        av += hd * Wv[(d << 5) + c];
    }
    q[(row << 5) + c] = aq;
    k[(row << 5) + c] = ak;
    v[(row << 5) + c] = av;
}

// ---------------------------------------------------------------- attention core
// 2 rows/lane, 512 rows/block, CLEN=64 j-chunk. K/V rows read DIRECTLY from
// global with wave-uniform addresses (TA coalesces to one L1 request +
// broadcast; 16KB chunk is L1-resident) -- no K/V LDS, no staging barrier
// dependency. Only x (alignment) stays in LDS. Partials: pm/ps [r][32] fp32;
// pacc [c][r] 80B record (32 h-dims bf16 pairs + x-partials fp32).
__global__ __launch_bounds__(256) void k_attn(const float* __restrict__ qg,
                                              const float* __restrict__ kg,
                                              const float* __restrict__ vg,
                                              const float* __restrict__ xin,
                                              const unsigned long long* __restrict__ maskg,
                                              float* __restrict__ pm,
                                              float* __restrict__ ps,
                                              unsigned* __restrict__ pacc) {
    __shared__ __attribute__((aligned(16))) float x_lds[CLEN * 4];

    const int t    = threadIdx.x;
    const int w    = t >> 6, lane = t & 63;
    const int rg   = blockIdx.x >> 5;        // 16 row-groups of 512 rows
    const int cid  = blockIdx.x & 31;        // 32 chunks
    const int bN   = (rg >> 2) << 11;
    const int j0   = cid << 6;
    const int r0   = (rg << 9) + (w << 6) + lane;
    const int r1   = r0 + 256;

    // ---- stage x chunk (alignment-safe float4 rows in LDS)
    if (t < CLEN) {
        const float* xp = xin + ((size_t)(bN + j0 + t)) * 3;
        float4 xv; xv.x = xp[0]; xv.y = xp[1]; xv.z = xp[2]; xv.w = 0.f;
        *(float4*)(x_lds + (t << 2)) = xv;
    }

    // ---- per-lane 2-row state (packed pairs)
    v2f q2a[16], q2b[16];
#pragma unroll
    for (int d = 0; d < 32; d += 4) {
        float4 a = *(const float4*)(qg + (((size_t)r0) << 5) + d);
        v2f lo; lo.x = a.x * C1F; lo.y = a.y * C1F;
        v2f hi; hi.x = a.z * C1F; hi.y = a.w * C1F;
        q2a[d >> 1] = lo; q2a[(d >> 1) + 1] = hi;
        float4 bb = *(const float4*)(qg + (((size_t)r1) << 5) + d);
        v2f lo2; lo2.x = bb.x * C1F; lo2.y = bb.y * C1F;
        v2f hi2; hi2.x = bb.z * C1F; hi2.y = bb.w * C1F;
        q2b[d >> 1] = lo2; q2b[(d >> 1) + 1] = hi2;
    }
    const float xa0 = xin[r0 * 3 + 0], xa1 = xin[r0 * 3 + 1], xa2 = xin[r0 * 3 + 2];
    const float xb0 = xin[r1 * 3 + 0], xb1 = xin[r1 * 3 + 1], xb2 = xin[r1 * 3 + 2];
    unsigned long long mwa = maskg[((size_t)r0 << 5) + cid];
    unsigned long long mwb = maskg[((size_t)r1 << 5) + cid];

    v2f acc2a[16], acc2b[16];
#pragma unroll
    for (int c2 = 0; c2 < 16; ++c2) {
        acc2a[c2].x = 0.f; acc2a[c2].y = 0.f;
        acc2b[c2].x = 0.f; acc2b[c2].y = 0.f;
    }
    float aa0 = 0.f, aa1 = 0.f, aa2 = 0.f;   // x-accumulator row0
    float ab0 = 0.f, ab1 = 0.f, ab2 = 0.f;   // x-accumulator row1
    float m0 = NEGF, m1 = NEGF, sum0 = 0.f, sum1 = 0.f;

    const float* kcp = kg + (((size_t)(bN + j0)) << 5);   // wave-uniform chunk base
    const float* vcp = vg + (((size_t)(bN + j0)) << 5);

    __syncthreads();     // x staging complete

#pragma unroll 4
    for (int jj = 0; jj < CLEN; ++jj) {
        const int bit0 = (int)(mwa & 1ULL); mwa >>= 1;
        const int bit1 = (int)(mwb & 1ULL); mwb >>= 1;
        const float4* kr = (const float4*)(kcp + (jj << 5));   // uniform addr -> L1 broadcast
        v2f Pa0 = {0.f,0.f}, Pa1 = {0.f,0.f}, Pb0 = {0.f,0.f}, Pb1 = {0.f,0.f};
#pragma unroll
        for (int c = 0; c < 8; ++c) {
            float4 k4 = kr[c];
            v2f kl; kl.x = k4.x; kl.y = k4.y;
            v2f kh; kh.x = k4.z; kh.y = k4.w;
            Pa0 = __builtin_elementwise_fma(q2a[2 * c],     kl, Pa0);
            Pa1 = __builtin_elementwise_fma(q2a[2 * c + 1], kh, Pa1);
            Pb0 = __builtin_elementwise_fma(q2b[2 * c],     kl, Pb0);
            Pb1 = __builtin_elementwise_fma(q2b[2 * c + 1], kh, Pb1);
        }
        v2f Sa = Pa0 + Pa1, Sb = Pb0 + Pb1;
        float dot0 = Sa.x + Sa.y, dot1 = Sb.x + Sb.y;

        float4 xj = *(const float4*)(x_lds + (jj << 2));
        float da0 = xa0 - xj.x, da1 = xa1 - xj.y, da2 = xa2 - xj.z;
        float db0 = xb0 - xj.x, db1 = xb1 - xj.y, db2 = xb2 - xj.z;
        float dista = fmaf(da2, da2, fmaf(da1, da1, da0 * da0));
        float distb = fmaf(db2, db2, fmaf(db1, db1, db0 * db0));
        float se0 = bit0 ? fmaf(dista, -LOG2E, dot0) : NEGF;
        float se1 = bit1 ? fmaf(distb, -LOG2E, dot1) : NEGF;

        if (__any(int(se0 - m0 > DEFER) | int(se1 - m1 > DEFER))) {
            float n0 = fmaxf(m0, se0), n1 = fmaxf(m1, se1);
            float al0 = exp2_fast(m0 - n0), al1 = exp2_fast(m1 - n1);
            m0 = n0; m1 = n1;
            sum0 *= al0; sum1 *= al1;
            v2f av0; av0.x = al0; av0.y = al0;
            v2f av1; av1.x = al1; av1.y = al1;
#pragma unroll
            for (int c2 = 0; c2 < 16; ++c2) { acc2a[c2] *= av0; acc2b[c2] *= av1; }
            aa0 *= al0; aa1 *= al0; aa2 *= al0;
            ab0 *= al1; ab1 *= al1; ab2 *= al1;
        }
        float p0 = exp2_fast(se0 - m0);
        float p1 = exp2_fast(se1 - m1);
        sum0 += p0; sum1 += p1;
        v2f pv0; pv0.x = p0; pv0.y = p0;
        v2f pv1; pv1.x = p1; pv1.y = p1;
        const float4* vr = (const float4*)(vcp + (jj << 5));   // uniform addr -> L1 broadcast
#pragma unroll
        for (int c = 0; c < 8; ++c) {
            float4 v4 = vr[c];
            v2f vl; vl.x = v4.x; vl.y = v4.y;
            v2f vh; vh.x = v4.z; vh.y = v4.w;
            acc2a[2 * c]     = __builtin_elementwise_fma(pv0, vl, acc2a[2 * c]);
            acc2a[2 * c + 1] = __builtin_elementwise_fma(pv0, vh, acc2a[2 * c + 1]);
            acc2b[2 * c]     = __builtin_elementwise_fma(pv1, vl, acc2b[2 * c]);
            acc2b[2 * c + 1] = __builtin_elementwise_fma(pv1, vh, acc2b[2 * c + 1]);
        }
        aa0 = fmaf(p0, xj.x, aa0); aa1 = fmaf(p0, xj.y, aa1); aa2 = fmaf(p0, xj.z, aa2);
        ab0 = fmaf(p1, xj.x, ab0); ab1 = fmaf(p1, xj.y, ab1); ab2 = fmaf(p1, xj.z, ab2);
    }

    // ---- write partials: stats [r][32] fp32; pacc record 16 u32 bf16-pairs + 4 f32
    pm[((size_t)r0 << 5) + cid] = m0;
    ps[((size_t)r0 << 5) + cid] = sum0;
    pm[((size_t)r1 << 5) + cid] = m1;
    ps[((size_t)r1 << 5) + cid] = sum1;
    {
        unsigned* pb = pacc + ((size_t)cid * NRTOT + r0) * PREC;
#pragma unroll
        for (int g4 = 0; g4 < 4; ++g4) {
            uint4 st; st.x = packbf(acc2a[4*g4]);   st.y = packbf(acc2a[4*g4+1]);
            st.z = packbf(acc2a[4*g4+2]); st.w = packbf(acc2a[4*g4+3]);
            *(uint4*)(pb + (g4 << 2)) = st;
        }
        float4 tl; tl.x = aa0; tl.y = aa1; tl.z = aa2; tl.w = 0.f;
        *(float4*)(pb + 16) = tl;
    }
    {
        unsigned* pb = pacc + ((size_t)cid * NRTOT + r1) * PREC;
#pragma unroll
        for (int g4 = 0; g4 < 4; ++g4) {
            uint4 st; st.x = packbf(acc2b[4*g4]);   st.y = packbf(acc2b[4*g4+1]);
            st.z = packbf(acc2b[4*g4+2]); st.w = packbf(acc2b[4*g4+3]);
            *(uint4*)(pb + (g4 << 2)) = st;
        }
        float4 tl; tl.x = ab0; tl.y = ab1; tl.z = ab2; tl.w = 0.f;
        *(float4*)(pb + 16) = tl;
    }
}

// ---------------------------------------------------------------- merge + epilogue + next-layer qkv
__global__ __launch_bounds__(256) void k_mergefin(const float* __restrict__ pm,
                                                  const float* __restrict__ ps,
                                                  const unsigned* __restrict__ pacc,
                                                  float* __restrict__ hg,
                                                  const float* __restrict__ xin,
                                                  float* __restrict__ xout,
                                                  const float* __restrict__ Wo,
                                                  const float* __restrict__ W1,
                                                  const float* __restrict__ W2,
                                                  const float* __restrict__ csp,
                                                  const float* __restrict__ Wqn,
                                                  const float* __restrict__ Wkn,
                                                  const float* __restrict__ Wvn,
                                                  float* __restrict__ qout,
                                                  float* __restrict__ kout,
                                                  float* __restrict__ vout) {
    __shared__ float wo_s[1024];
    __shared__ float w1_s[2048];
    __shared__ float w2_s[2048];
    __shared__ float wq_s[1024];
    __shared__ float wk_s[1024];
    __shared__ float wv_s[1024];
    __shared__ float ad_s[4][40];
    __shared__ float h1_s[4][36];
    __shared__ float h2_s[4][36];
    __shared__ float f_s[4][64];

    const int t = threadIdx.x, w = t >> 6, lane = t & 63;
    for (int i = t; i < 1024; i += 256) wo_s[i] = Wo[i];
    for (int i = t; i < 2048; i += 256) { w1_s[i] = W1[i]; w2_s[i] = W2[i]; }
    if (Wqn) {
        for (int i = t; i < 1024; i += 256) {
            wq_s[i] = Wqn[i]; wk_s[i] = Wkn[i]; wv_s[i] = Wvn[i];
        }
    }
    __syncthreads();

    const int r = (blockIdx.x << 2) + w;

    // merge stats across 32 chunks ([r][32] layout -> coalesced per wave)
    float pmv = NEGF, psv = 0.f;
    if (lane < NCHUNK) { pmv = pm[((size_t)r << 5) + lane]; psv = ps[((size_t)r << 5) + lane]; }
    float m_g = pmv;
#pragma unroll
    for (int off = 1; off < 64; off <<= 1) m_g = fmaxf(m_g, __shfl_xor(m_g, off));
    float scv = (lane < NCHUNK) ? exp2_fast(pmv - m_g) : 0.f;
    float sg = scv * psv;
#pragma unroll
    for (int off = 1; off < 64; off <<= 1) sg += __shfl_xor(sg, off);
    const float rinv = 1.0f / sg;

    // merged accumulator, lane = d. record: u32 j = dims 2j(lo),2j+1(hi); +fp32 tail
    const int off32 = (lane < 32) ? (lane >> 1) : (16 + ((lane - 32) & 3));
    const bool isTail = lane >= 32;
    const bool hiHalf = lane & 1;
    float ad = 0.f;
#pragma unroll
    for (int c = 0; c < NCHUNK; ++c) {
        float scc = __shfl(scv, c);
        unsigned u = pacc[((size_t)c * NRTOT + r) * PREC + off32];
        float f = isTail ? __builtin_bit_cast(float, u)
                         : __builtin_bit_cast(float, hiHalf ? (u & 0xffff0000u) : (u << 16));
        ad = fmaf(scc, f, ad);
    }
    if (lane < 35) ad_s[w][lane] = ad;

    // Wo matmul: lane&31 = col (both halves compute redundantly)
    const int col = lane & 31;
    float hv = 0.f;
#pragma unroll
    for (int d = 0; d < 32; ++d) hv = fmaf(ad_s[w][d], wo_s[(d << 5) + col], hv);
    float h1 = 0.f;
    if (lane < 32) { h1 = hg[(((size_t)r) << 5) + lane] + hv * rinv; h1_s[w][lane] = h1; }

    // FF up: lane = u (64)
    float f = 0.f;
#pragma unroll
    for (int d = 0; d < 32; ++d) f = fmaf(h1_s[w][d], w1_s[(d << 6) + lane], f);
    f = fmaxf(f, 0.f);
    f_s[w][lane] = f;

    // FF down + residual: lane<32 = col
    if (lane < 32) {
        float v2a = 0.f;
#pragma unroll
        for (int u = 0; u < 64; ++u) v2a = fmaf(f_s[w][u], w2_s[(u << 5) + lane], v2a);
        float hnew = h1 + v2a;
        hg[(((size_t)r) << 5) + lane] = hnew;
        h2_s[w][lane] = hnew;
    }

    // equivariant x update
    if (lane < 3) {
        float o  = ad_s[w][32 + lane] * rinv;
        float xi = xin[r * 3 + lane];
        xout[r * 3 + lane] = xi + csp[0] * (xi - o);
    }

    // fused next-layer qkv (lane<32 = output column)
    if (Wqn && lane < 32) {
        float aq = 0.f, ak = 0.f, av = 0.f;
#pragma unroll
        for (int d = 0; d < 32; ++d) {
            float hd = h2_s[w][d];
            aq = fmaf(hd, wq_s[(d << 5) + lane], aq);
            ak = fmaf(hd, wk_s[(d << 5) + lane], ak);
            av = fmaf(hd, wv_s[(d << 5) + lane], av);
        }
        qout[(((size_t)r) << 5) + lane] = aq;
        kout[(((size_t)r) << 5) + lane] = ak;
        vout[(((size_t)r) << 5) + lane] = av;
    }
}

// ---------------------------------------------------------------- pooling stage 1 (parallel)
__global__ __launch_bounds__(256) void k_pool(const float* __restrict__ h,
                                              float* __restrict__ pool_ws) {
    const int b = blockIdx.x >> 5, sub = blockIdx.x & 31;
    const int t = threadIdx.x, c = t & 31, g = t >> 5;
    float s = 0.f;
#pragma unroll
    for (int i = 0; i < 8; ++i) {
        int row = (sub << 6) + (g << 3) + i;
        s += h[(((size_t)((b << 11) + row)) << 5) + c];
    }
    __shared__ float pool[8][32];
    pool[g][c] = s;
    __syncthreads();
    if (t < 32) {
        float ss = 0.f;
#pragma unroll
        for (int gg = 0; gg < 8; ++gg) ss += pool[gg][t];
        pool_ws[((b << 5) + sub) * 32 + t] = ss;
    }
}

// ---------------------------------------------------------------- head (tiny)
__global__ __launch_bounds__(256) void k_head(const float* __restrict__ pool_ws,
                                              const float* __restrict__ Wf1,
                                              const float* __restrict__ bf1,
                                              const float* __restrict__ Wf2,
                                              const float* __restrict__ bf2,
                                              float* __restrict__ out) {
    __shared__ float pooled[4][32];
    __shared__ float a1[4][16];
    const int t = threadIdx.x;
    if (t < 128) {
        int b = t >> 5, c = t & 31;
        float ss = 0.f;
#pragma unroll
        for (int sub = 0; sub < 32; ++sub) ss += pool_ws[((b << 5) + sub) * 32 + c];
        pooled[b][c] = ss * (1.0f / N_);
    }
    __syncthreads();
    if (t < 64) {
        int b = t >> 4, u = t & 15;
        float a = bf1[u];
#pragma unroll
        for (int d = 0; d < 32; ++d) a += pooled[b][d] * Wf1[(d << 4) + u];
        a1[b][u] = fmaxf(a, 0.f);
    }
    __syncthreads();
    if (t < 12) {
        int b = t / 3, o = t - b * 3;
        float v = bf2[o];
#pragma unroll
        for (int e = 0; e < 16; ++e) v += a1[b][e] * Wf2[e * 3 + o];
        out[b * 3 + o] = v;
    }
}

// ---------------------------------------------------------------- launch
extern "C" void kernel_launch(void* const* d_in, const int* in_sizes, int n_in,
                              void* d_out, int out_size, void* d_ws, size_t ws_size,
                              hipStream_t stream) {
    const float* feats = (const float*)d_in[0];
    const float* coors = (const float*)d_in[1];
    const int*   adj   = (const int*)d_in[2];
    const float* W_in  = (const float*)d_in[3];
    const float* Wq    = (const float*)d_in[4];
    const float* Wk    = (const float*)d_in[5];
    const float* Wv    = (const float*)d_in[6];
    const float* Wo    = (const float*)d_in[7];
    const float* W1    = (const float*)d_in[8];
    const float* W2    = (const float*)d_in[9];
    const float* csc   = (const float*)d_in[10];
    const float* Wf1   = (const float*)d_in[11];
    const float* bf1   = (const float*)d_in[12];
    const float* Wf2   = (const float*)d_in[13];
    const float* bf2   = (const float*)d_in[14];

    const size_t BNH = (size_t)4 * N_ * H_;   // 262144
    float* ws = (float*)d_ws;
    float* h  = ws;
    float* q  = ws + BNH;
    float* k  = ws + 2 * BNH;
    float* v  = ws + 3 * BNH;
    float* x0 = ws + 4 * BNH;                          // 24576 floats
    float* x1 = x0 + (size_t)4 * N_ * 3;
    unsigned long long* mask = (unsigned long long*)(x1 + (size_t)4 * N_ * 3);  // 262144 u64
    float* pm   = (float*)(mask + 262144);             // 32*8192 floats
    float* ps   = pm + (size_t)NCHUNK * NRTOT;
    unsigned* pacc = (unsigned*)(ps + (size_t)NCHUNK * NRTOT);  // 32*8192*20 u32 (21MB)
    float* pool_ws = (float*)(pacc + (size_t)NCHUNK * NRTOT * PREC);  // 4096 floats

    k_adjmask<<<65536, 256, 0, stream>>>(adj, mask);
    k_init_qkv<<<1024, 256, 0, stream>>>(feats, W_in, Wq, Wk, Wv, h, q, k, v);

    const float* xin[3]  = {coors, x0, x1};
    float*       xout[3] = {x0, x1, x0};
    for (int l = 0; l < 3; ++l) {
        k_attn<<<512, 256, 0, stream>>>(q, k, v, xin[l], mask, pm, ps, pacc);
        const bool last = (l == 2);
        k_mergefin<<<2048, 256, 0, stream>>>(pm, ps, pacc, h, xin[l], xout[l],
                                             Wo + l * 1024, W1 + l * 2048, W2 + l * 2048,
                                             csc + l,
                                             last ? nullptr : Wq + (l + 1) * 1024,
                                             last ? nullptr : Wk + (l + 1) * 1024,
                                             last ? nullptr : Wv + (l + 1) * 1024,
                                             q, k, v);
    }
    k_pool<<<128, 256, 0, stream>>>(h, pool_ws);
    k_head<<<1, 256, 0, stream>>>(pool_ws, Wf1, bf1, Wf2, bf2, (float*)d_out);
}

// Round 17
// 154.769 us; speedup vs baseline: 2.2656x; 2.2656x over previous
//
#include <hip/hip_runtime.h>
#include <cstddef>
#include <cstdint>

#define N_     2048
#define H_     32
#define NEGF   (-1.0e30f)
#define LOG2E  1.4426950408889634f
#define C1F    (0.17677669529663687f * 1.4426950408889634f)   // (1/sqrt(32))*log2e
#define DEFER  16.0f
#define NCHUNK 32
#define CLEN   64             // N_/NCHUNK
#define NRTOT  8192           // B*N
#define PREC   20             // u32 per (chunk,row) pacc record: 16 bf16-pair + 4 f32

#define AS1 __attribute__((address_space(1)))
#define AS3 __attribute__((address_space(3)))

typedef unsigned short ushortT;
typedef short v8s __attribute__((ext_vector_type(8)));   // 8 bf16 = 4 VGPR (MFMA A/B frag)
typedef float v4f __attribute__((ext_vector_type(4)));   // MFMA C/D frag

__device__ __forceinline__ float exp2_fast(float x) {
    float r;
    asm("v_exp_f32 %0, %1" : "=v"(r) : "v"(x));
    return r;
}

// RNE float -> bf16 (u16 in low bits)
__device__ __forceinline__ unsigned f2bf(float x) {
    unsigned u = __builtin_bit_cast(unsigned, x);
    return (u + 0x7FFFu + ((u >> 16) & 1u)) >> 16;
}

// ---------------------------------------------------------------- adj -> bitmask
__global__ __launch_bounds__(256) void k_adjmask(const int* __restrict__ adj,
                                                 unsigned long long* __restrict__ mask) {
    size_t idx = (size_t)blockIdx.x * 256 + threadIdx.x;     // over B*N*N
    unsigned long long m = __ballot(adj[idx] != 0);
    if ((threadIdx.x & 63) == 0) mask[idx >> 6] = m;
}

// ---------------------------------------------------------------- fused h-init + layer-0 qkv (bf16 q/k/v)
__global__ __launch_bounds__(256) void k_init_qkv(const float* __restrict__ feats,
                                                  const float* __restrict__ W_in,
                                                  const float* __restrict__ Wq,
                                                  const float* __restrict__ Wk,
                                                  const float* __restrict__ Wv,
                                                  float* __restrict__ h,
                                                  ushortT* __restrict__ qb,
                                                  ushortT* __restrict__ kb,
                                                  ushortT* __restrict__ vb) {
    __shared__ float hs[8][33];
    int t = threadIdx.x;
    int rl = t >> 5, c = t & 31;
    int row = blockIdx.x * 8 + rl;
    float f0 = feats[row * 3 + 0], f1 = feats[row * 3 + 1], f2 = feats[row * 3 + 2];
    float hv = f0 * W_in[c] + f1 * W_in[32 + c] + f2 * W_in[64 + c];
    hs[rl][c] = hv;
    h[(row << 5) + c] = hv;
    __syncthreads();
    float aq = 0.f, ak = 0.f, av = 0.f;
#pragma unroll
    for (int d = 0; d < 32; ++d) {
        float hd = hs[rl][d];
        aq += hd * Wq[(d << 5) + c];
        ak += hd * Wk[(d << 5) + c];
        av += hd * Wv[(d << 5) + c];
    }
    qb[(row << 5) + c] = (ushortT)f2bf(aq * C1F);   // q pre-scaled into log2 domain
    kb[(row << 5) + c] = (ushortT)f2bf(ak);
    vb[(row << 5) + c] = (ushortT)f2bf(av);
}

// ---------------------------------------------------------------- attention core (MFMA)
// 4 waves x 16 q-rows, CLEN=64 j-chunk, grid 4096. Per 32-j tile per wave:
//   S^T[j][q] = mfma(K-tile[16x32], Q^T)  (2 tiles)   [C/D: row=4g+reg, col=lane&15]
//   fp32 softmax/dist2/mask on S^T; P packed bf16 -> per-wave LDS transpose
//   O^T[d][q] += mfma(V^T-tile[16x32j], P^T)  (2 d-tiles)
// x-accumulator in fp32 VALU. Partials identical format to r13/r16.
__global__ __launch_bounds__(256) void k_attn(const ushortT* __restrict__ qb,
                                              const ushortT* __restrict__ kb,
                                              const ushortT* __restrict__ vb,
                                              const float* __restrict__ xin,
                                              const unsigned long long* __restrict__ maskg,
                                              float* __restrict__ pm,
                                              float* __restrict__ ps,
                                              unsigned* __restrict__ pacc) {
    __shared__ __attribute__((aligned(16))) ushortT k_lds[64 * 32];    // [j][d] bf16, 4KB
    __shared__ __attribute__((aligned(16))) ushortT vt_lds[32 * 72];   // [d][j] stride 72, 4.5KB
    __shared__ __attribute__((aligned(16))) float4  x_lds[64];         // 1KB
    __shared__ __attribute__((aligned(16))) ushortT p_lds[4][16 * 40]; // per-wave P^T, 5KB

    const int t = threadIdx.x;
    const int w = t >> 6, l = t & 63;
    const int g = l >> 4, q = l & 15;
    const int rowblk = blockIdx.x >> 5;      // 128 row-blocks of 64 rows
    const int cid    = blockIdx.x & 31;      // 32 chunks
    const int bN = (rowblk >> 5) << 11;      // 32 row-blocks per batch
    const int j0 = cid << 6;
    const int rq = rowblk * 64 + w * 16 + q; // this lane's q-row

    // ---- stage K chunk (bf16, 64x32 = 4KB, one 16B gload_lds per thread)
    __builtin_amdgcn_global_load_lds(
        (const AS1 void*)((const char*)(kb + (((size_t)(bN + j0)) << 5)) + t * 16),
        (AS3 void*)((char*)k_lds + t * 16), 16, 0, 0);
    // ---- stage V^T (reg transpose): thread handles j=t&63, d-slice 8*(t>>6)
    {
        const int j = t & 63, grp = t >> 6;
        const uint4 vv = *(const uint4*)(vb + (((size_t)(bN + j0 + j)) << 5) + grp * 8);
        unsigned arr[4] = {vv.x, vv.y, vv.z, vv.w};
#pragma unroll
        for (int ii = 0; ii < 4; ++ii) {
            vt_lds[(grp * 8 + 2 * ii) * 72 + j]     = (ushortT)(arr[ii] & 0xffffu);
            vt_lds[(grp * 8 + 2 * ii + 1) * 72 + j] = (ushortT)(arr[ii] >> 16);
        }
    }
    if (t < 64) {
        const float* xp = xin + ((size_t)(bN + j0 + t)) * 3;
        float4 xv; xv.x = xp[0]; xv.y = xp[1]; xv.z = xp[2]; xv.w = 0.f;
        x_lds[t] = xv;
    }

    // ---- per-lane state
    const v8s qf = *(const v8s*)(qb + (((size_t)rq) << 5) + g * 8);  // Q B-frag (row q, d=8g..)
    const float xi0 = xin[rq * 3 + 0], xi1 = xin[rq * 3 + 1], xi2 = xin[rq * 3 + 2];
    const unsigned long long mw = maskg[(((size_t)rq) << 5) + cid];

    v4f oA = {0.f, 0.f, 0.f, 0.f}, oB = {0.f, 0.f, 0.f, 0.f};
    float m = NEGF, sum = 0.f;
    float xa0 = 0.f, xa1 = 0.f, xa2 = 0.f;

    __syncthreads();     // staging complete

    ushortT* pw = &p_lds[w][0];

#pragma unroll
    for (int half = 0; half < 2; ++half) {
        const int jt = half * 32;
        // --- QK^T: S^T tiles (j 0-15, 16-31 of this 32-block)
        v8s kA = *(const v8s*)(k_lds + (jt + q) * 32 + g * 8);
        v8s kB = *(const v8s*)(k_lds + (jt + 16 + q) * 32 + g * 8);
        v4f zero = {0.f, 0.f, 0.f, 0.f};
        v4f sA = __builtin_amdgcn_mfma_f32_16x16x32_bf16(kA, qf, zero, 0, 0, 0);
        v4f sB = __builtin_amdgcn_mfma_f32_16x16x32_bf16(kB, qf, zero, 0, 0, 0);

        // --- mask + dist2 + logits (fp32)
        float se[8];
        float4 xjA[4], xjB[4];
        float pot = NEGF;
#pragma unroll
        for (int reg = 0; reg < 4; ++reg) {
            const int jA = jt + 4 * g + reg, jB = jA + 16;
            xjA[reg] = x_lds[jA];
            xjB[reg] = x_lds[jB];
            float dA0 = xi0 - xjA[reg].x, dA1 = xi1 - xjA[reg].y, dA2 = xi2 - xjA[reg].z;
            float dB0 = xi0 - xjB[reg].x, dB1 = xi1 - xjB[reg].y, dB2 = xi2 - xjB[reg].z;
            float distA = fmaf(dA2, dA2, fmaf(dA1, dA1, dA0 * dA0));
            float distB = fmaf(dB2, dB2, fmaf(dB1, dB1, dB0 * dB0));
            const int bA = (int)((mw >> jA) & 1ULL);
            const int bB = (int)((mw >> jB) & 1ULL);
            se[reg]     = bA ? fmaf(distA, -LOG2E, sA[reg]) : NEGF;
            se[4 + reg] = bB ? fmaf(distB, -LOG2E, sB[reg]) : NEGF;
            pot = fmaxf(pot, fmaxf(se[reg], se[4 + reg]));
        }
        pot = fmaxf(pot, __shfl_xor(pot, 16));
        pot = fmaxf(pot, __shfl_xor(pot, 32));
        if (__any(pot - m > DEFER)) {
            float n2 = fmaxf(m, pot);
            float al = exp2_fast(m - n2);
            m = n2; sum *= al;
            v4f alv = {al, al, al, al};
            oA *= alv; oB *= alv;
            xa0 *= al; xa1 *= al; xa2 *= al;
        }
        float p[8];
#pragma unroll
        for (int i = 0; i < 8; ++i) { p[i] = exp2_fast(se[i] - m); sum += p[i]; }
        // x-accumulator (fp32, lane covers its own j's; reduced at end)
#pragma unroll
        for (int reg = 0; reg < 4; ++reg) {
            xa0 = fmaf(p[reg], xjA[reg].x, fmaf(p[4 + reg], xjB[reg].x, xa0));
            xa1 = fmaf(p[reg], xjA[reg].y, fmaf(p[4 + reg], xjB[reg].y, xa1));
            xa2 = fmaf(p[reg], xjA[reg].z, fmaf(p[4 + reg], xjB[reg].z, xa2));
        }
        // --- pack P -> per-wave LDS [q][j-local], stride 40 shorts
        uint2 wA, wB;
        wA.x = f2bf(p[0]) | (f2bf(p[1]) << 16);
        wA.y = f2bf(p[2]) | (f2bf(p[3]) << 16);
        wB.x = f2bf(p[4]) | (f2bf(p[5]) << 16);
        wB.y = f2bf(p[6]) | (f2bf(p[7]) << 16);
        *(uint2*)(pw + q * 40 + 4 * g)      = wA;   // j-local 4g..4g+3
        *(uint2*)(pw + q * 40 + 16 + 4 * g) = wB;   // j-local 16+4g..+3
        // --- PV: O^T += V^T-tile * P^T
        v8s pf = *(const v8s*)(pw + q * 40 + 8 * g);            // B-frag: col q, k=8g..8g+7
        v8s vA = *(const v8s*)(vt_lds + q * 72 + jt + 8 * g);          // d = q
        v8s vB = *(const v8s*)(vt_lds + (16 + q) * 72 + jt + 8 * g);   // d = 16+q
        oA = __builtin_amdgcn_mfma_f32_16x16x32_bf16(vA, pf, oA, 0, 0, 0);
        oB = __builtin_amdgcn_mfma_f32_16x16x32_bf16(vB, pf, oB, 0, 0, 0);
    }

    // ---- reduce per-lane partials across the 4 groups of column q
    sum += __shfl_xor(sum, 16); sum += __shfl_xor(sum, 32);
    xa0 += __shfl_xor(xa0, 16); xa0 += __shfl_xor(xa0, 32);
    xa1 += __shfl_xor(xa1, 16); xa1 += __shfl_xor(xa1, 32);
    xa2 += __shfl_xor(xa2, 16); xa2 += __shfl_xor(xa2, 32);

    // ---- write partials (record format identical to r16's mergefin reader)
    unsigned* pb = pacc + ((size_t)cid * NRTOT + rq) * PREC;
    uint2 rA, rB;
    rA.x = f2bf(oA[0]) | (f2bf(oA[1]) << 16);   // dims 4g,4g+1
    rA.y = f2bf(oA[2]) | (f2bf(oA[3]) << 16);   // dims 4g+2,4g+3
    rB.x = f2bf(oB[0]) | (f2bf(oB[1]) << 16);   // dims 16+4g..
    rB.y = f2bf(oB[2]) | (f2bf(oB[3]) << 16);
    *(uint2*)(pb + 2 * g)     = rA;
    *(uint2*)(pb + 8 + 2 * g) = rB;
    if (g == 0) {
        float4 tl; tl.x = xa0; tl.y = xa1; tl.z = xa2; tl.w = 0.f;
        *(float4*)(pb + 16) = tl;
        pm[(((size_t)rq) << 5) + cid] = m;
        ps[(((size_t)rq) << 5) + cid] = sum;
    }
}

// ---------------------------------------------------------------- merge + epilogue + next-layer qkv
__global__ __launch_bounds__(256) void k_mergefin(const float* __restrict__ pm,
                                                  const float* __restrict__ ps,
                                                  const unsigned* __restrict__ pacc,
                                                  float* __restrict__ hg,
                                                  const float* __restrict__ xin,
                                                  float* __restrict__ xout,
                                                  const float* __restrict__ Wo,
                                                  const float* __restrict__ W1,
                                                  const float* __restrict__ W2,
                                                  const float* __restrict__ csp,
                                                  const float* __restrict__ Wqn,
                                                  const float* __restrict__ Wkn,
                                                  const float* __restrict__ Wvn,
                                                  ushortT* __restrict__ qout,
                                                  ushortT* __restrict__ kout,
                                                  ushortT* __restrict__ vout) {
    __shared__ float wo_s[1024];
    __shared__ float w1_s[2048];
    __shared__ float w2_s[2048];
    __shared__ float wq_s[1024];
    __shared__ float wk_s[1024];
    __shared__ float wv_s[1024];
    __shared__ float ad_s[4][40];
    __shared__ float h1_s[4][36];
    __shared__ float h2_s[4][36];
    __shared__ float f_s[4][64];

    const int t = threadIdx.x, w = t >> 6, lane = t & 63;
    for (int i = t; i < 1024; i += 256) wo_s[i] = Wo[i];
    for (int i = t; i < 2048; i += 256) { w1_s[i] = W1[i]; w2_s[i] = W2[i]; }
    if (Wqn) {
        for (int i = t; i < 1024; i += 256) {
            wq_s[i] = Wqn[i]; wk_s[i] = Wkn[i]; wv_s[i] = Wvn[i];
        }
    }
    __syncthreads();

    const int r = (blockIdx.x << 2) + w;

    // merge stats across 32 chunks ([r][32] layout -> coalesced per wave)
    float pmv = NEGF, psv = 0.f;
    if (lane < NCHUNK) { pmv = pm[((size_t)r << 5) + lane]; psv = ps[((size_t)r << 5) + lane]; }
    float m_g = pmv;
#pragma unroll
    for (int off = 1; off < 64; off <<= 1) m_g = fmaxf(m_g, __shfl_xor(m_g, off));
    float scv = (lane < NCHUNK) ? exp2_fast(pmv - m_g) : 0.f;
    float sg = scv * psv;
#pragma unroll
    for (int off = 1; off < 64; off <<= 1) sg += __shfl_xor(sg, off);
    const float rinv = 1.0f / sg;

    // merged accumulator, lane = d. record: u32 j = dims 2j(lo),2j+1(hi); +fp32 tail
    const int off32 = (lane < 32) ? (lane >> 1) : (16 + ((lane - 32) & 3));
    const bool isTail = lane >= 32;
    const bool hiHalf = lane & 1;
    float ad = 0.f;
#pragma unroll
    for (int c = 0; c < NCHUNK; ++c) {
        float scc = __shfl(scv, c);
        unsigned u = pacc[((size_t)c * NRTOT + r) * PREC + off32];
        float f = isTail ? __builtin_bit_cast(float, u)
                         : __builtin_bit_cast(float, hiHalf ? (u & 0xffff0000u) : (u << 16));
        ad = fmaf(scc, f, ad);
    }
    if (lane < 35) ad_s[w][lane] = ad;

    // Wo matmul: lane&31 = col (both halves compute redundantly)
    const int col = lane & 31;
    float hv = 0.f;
#pragma unroll
    for (int d = 0; d < 32; ++d) hv = fmaf(ad_s[w][d], wo_s[(d << 5) + col], hv);
    float h1 = 0.f;
    if (lane < 32) { h1 = hg[(((size_t)r) << 5) + lane] + hv * rinv; h1_s[w][lane] = h1; }

    // FF up: lane = u (64)
    float f = 0.f;
#pragma unroll
    for (int d = 0; d < 32; ++d) f = fmaf(h1_s[w][d], w1_s[(d << 6) + lane], f);
    f = fmaxf(f, 0.f);
    f_s[w][lane] = f;

    // FF down + residual: lane<32 = col
    if (lane < 32) {
        float v2a = 0.f;
#pragma unroll
        for (int u = 0; u < 64; ++u) v2a = fmaf(f_s[w][u], w2_s[(u << 5) + lane], v2a);
        float hnew = h1 + v2a;
        hg[(((size_t)r) << 5) + lane] = hnew;
        h2_s[w][lane] = hnew;
    }

    // equivariant x update
    if (lane < 3) {
        float o  = ad_s[w][32 + lane] * rinv;
        float xi = xin[r * 3 + lane];
        xout[r * 3 + lane] = xi + csp[0] * (xi - o);
    }

    // fused next-layer qkv (lane<32 = output column), bf16 out
    if (Wqn && lane < 32) {
        float aq = 0.f, ak = 0.f, av = 0.f;
#pragma unroll
        for (int d = 0; d < 32; ++d) {
            float hd = h2_s[w][d];
            aq = fmaf(hd, wq_s[(d << 5) + lane], aq);
            ak = fmaf(hd, wk_s[(d << 5) + lane], ak);
            av = fmaf(hd, wv_s[(d << 5) + lane], av);
        }
        qout[(((size_t)r) << 5) + lane] = (ushortT)f2bf(aq * C1F);
        kout[(((size_t)r) << 5) + lane] = (ushortT)f2bf(ak);
        vout[(((size_t)r) << 5) + lane] = (ushortT)f2bf(av);
    }
}

// ---------------------------------------------------------------- pooling stage 1 (parallel)
__global__ __launch_bounds__(256) void k_pool(const float* __restrict__ h,
                                              float* __restrict__ pool_ws) {
    const int b = blockIdx.x >> 5, sub = blockIdx.x & 31;
    const int t = threadIdx.x, c = t & 31, g = t >> 5;
    float s = 0.f;
#pragma unroll
    for (int i = 0; i < 8; ++i) {
        int row = (sub << 6) + (g << 3) + i;
        s += h[(((size_t)((b << 11) + row)) << 5) + c];
    }
    __shared__ float pool[8][32];
    pool[g][c] = s;
    __syncthreads();
    if (t < 32) {
        float ss = 0.f;
#pragma unroll
        for (int gg = 0; gg < 8; ++gg) ss += pool[gg][t];
        pool_ws[((b << 5) + sub) * 32 + t] = ss;
    }
}

// ---------------------------------------------------------------- head (tiny)
__global__ __launch_bounds__(256) void k_head(const float* __restrict__ pool_ws,
                                              const float* __restrict__ Wf1,
                                              const float* __restrict__ bf1,
                                              const float* __restrict__ Wf2,
                                              const float* __restrict__ bf2,
                                              float* __restrict__ out) {
    __shared__ float pooled[4][32];
    __shared__ float a1[4][16];
    const int t = threadIdx.x;
    if (t < 128) {
        int b = t >> 5, c = t & 31;
        float ss = 0.f;
#pragma unroll
        for (int sub = 0; sub < 32; ++sub) ss += pool_ws[((b << 5) + sub) * 32 + c];
        pooled[b][c] = ss * (1.0f / N_);
    }
    __syncthreads();
    if (t < 64) {
        int b = t >> 4, u = t & 15;
        float a = bf1[u];
#pragma unroll
        for (int d = 0; d < 32; ++d) a += pooled[b][d] * Wf1[(d << 4) + u];
        a1[b][u] = fmaxf(a, 0.f);
    }
    __syncthreads();
    if (t < 12) {
        int b = t / 3, o = t - b * 3;
        float v = bf2[o];
#pragma unroll
        for (int e = 0; e < 16; ++e) v += a1[b][e] * Wf2[e * 3 + o];
        out[b * 3 + o] = v;
    }
}

// ---------------------------------------------------------------- launch
extern "C" void kernel_launch(void* const* d_in, const int* in_sizes, int n_in,
                              void* d_out, int out_size, void* d_ws, size_t ws_size,
                              hipStream_t stream) {
    const float* feats = (const float*)d_in[0];
    const float* coors = (const float*)d_in[1];
    const int*   adj   = (const int*)d_in[2];
    const float* W_in  = (const float*)d_in[3];
    const float* Wq    = (const float*)d_in[4];
    const float* Wk    = (const float*)d_in[5];
    const float* Wv    = (const float*)d_in[6];
    const float* Wo    = (const float*)d_in[7];
    const float* W1    = (const float*)d_in[8];
    const float* W2    = (const float*)d_in[9];
    const float* csc   = (const float*)d_in[10];
    const float* Wf1   = (const float*)d_in[11];
    const float* bf1   = (const float*)d_in[12];
    const float* Wf2   = (const float*)d_in[13];
    const float* bf2   = (const float*)d_in[14];

    const size_t BNH = (size_t)4 * N_ * H_;   // 262144
    float* ws = (float*)d_ws;
    float* h  = ws;
    ushortT* qb = (ushortT*)(ws + BNH);       // BNH ushorts each (512KB)
    ushortT* kb = qb + BNH;
    ushortT* vb = kb + BNH;
    float* x0 = (float*)(vb + BNH);           // 24576 floats
    float* x1 = x0 + (size_t)4 * N_ * 3;
    unsigned long long* mask = (unsigned long long*)(x1 + (size_t)4 * N_ * 3);  // 262144 u64
    float* pm   = (float*)(mask + 262144);    // 32*8192 floats
    float* ps   = pm + (size_t)NCHUNK * NRTOT;
    unsigned* pacc = (unsigned*)(ps + (size_t)NCHUNK * NRTOT);  // 32*8192*20 u32 (21MB)
    float* pool_ws = (float*)(pacc + (size_t)NCHUNK * NRTOT * PREC);  // 4096 floats

    k_adjmask<<<65536, 256, 0, stream>>>(adj, mask);
    k_init_qkv<<<1024, 256, 0, stream>>>(feats, W_in, Wq, Wk, Wv, h, qb, kb, vb);

    const float* xin[3]  = {coors, x0, x1};
    float*       xout[3] = {x0, x1, x0};
    for (int l = 0; l < 3; ++l) {
        k_attn<<<4096, 256, 0, stream>>>(qb, kb, vb, xin[l], mask, pm, ps, pacc);
        const bool last = (l == 2);
        k_mergefin<<<2048, 256, 0, stream>>>(pm, ps, pacc, h, xin[l], xout[l],
                                             Wo + l * 1024, W1 + l * 2048, W2 + l * 2048,
                                             csc + l,
                                             last ? nullptr : Wq + (l + 1) * 1024,
                                             last ? nullptr : Wk + (l + 1) * 1024,
                                             last ? nullptr : Wv + (l + 1) * 1024,
                                             qb, kb, vb);
    }
    k_pool<<<128, 256, 0, stream>>>(h, pool_ws);
    k_head<<<1, 256, 0, stream>>>(pool_ws, Wf1, bf1, Wf2, bf2, (float*)d_out);
}

// Round 18
// 148.797 us; speedup vs baseline: 2.3566x; 1.0401x over previous
//
#include <hip/hip_runtime.h>
#include <cstddef>
#include <cstdint>

#define N_     2048
#define H_     32
#define NEGF   (-1.0e30f)
#define LOG2E  1.4426950408889634f
#define C1F    (0.17677669529663687f * 1.4426950408889634f)   // (1/sqrt(32))*log2e
#define DEFER  16.0f
#define NCHUNK 8
#define CLEN   256            // N_/NCHUNK
#define NRTOT  8192           // B*N
#define PREC   20             // u32 per (chunk,row) pacc record: 16 bf16-pair + 4 f32

#define AS1 __attribute__((address_space(1)))
#define AS3 __attribute__((address_space(3)))

typedef unsigned short ushortT;
typedef short v8s __attribute__((ext_vector_type(8)));   // 8 bf16 = 4 VGPR (MFMA A/B frag)
typedef float v4f __attribute__((ext_vector_type(4)));   // MFMA C/D frag

__device__ __forceinline__ float exp2_fast(float x) {
    float r;
    asm("v_exp_f32 %0, %1" : "=v"(r) : "v"(x));
    return r;
}

// RNE float -> bf16 (u16 in low bits)
__device__ __forceinline__ unsigned f2bf(float x) {
    unsigned u = __builtin_bit_cast(unsigned, x);
    return (u + 0x7FFFu + ((u >> 16) & 1u)) >> 16;
}

// ---------------------------------------------------------------- adj -> bitmask
__global__ __launch_bounds__(256) void k_adjmask(const int* __restrict__ adj,
                                                 unsigned long long* __restrict__ mask) {
    size_t idx = (size_t)blockIdx.x * 256 + threadIdx.x;     // over B*N*N
    unsigned long long m = __ballot(adj[idx] != 0);
    if ((threadIdx.x & 63) == 0) mask[idx >> 6] = m;
}

// ---------------------------------------------------------------- fused h-init + layer-0 qkv (bf16 q/k/v)
__global__ __launch_bounds__(256) void k_init_qkv(const float* __restrict__ feats,
                                                  const float* __restrict__ W_in,
                                                  const float* __restrict__ Wq,
                                                  const float* __restrict__ Wk,
                                                  const float* __restrict__ Wv,
                                                  float* __restrict__ h,
                                                  ushortT* __restrict__ qb,
                                                  ushortT* __restrict__ kb,
                                                  ushortT* __restrict__ vb) {
    __shared__ float hs[8][33];
    int t = threadIdx.x;
    int rl = t >> 5, c = t & 31;
    int row = blockIdx.x * 8 + rl;
    float f0 = feats[row * 3 + 0], f1 = feats[row * 3 + 1], f2 = feats[row * 3 + 2];
    float hv = f0 * W_in[c] + f1 * W_in[32 + c] + f2 * W_in[64 + c];
    hs[rl][c] = hv;
    h[(row << 5) + c] = hv;
    __syncthreads();
    float aq = 0.f, ak = 0.f, av = 0.f;
#pragma unroll
    for (int d = 0; d < 32; ++d) {
        float hd = hs[rl][d];
        aq += hd * Wq[(d << 5) + c];
        ak += hd * Wk[(d << 5) + c];
        av += hd * Wv[(d << 5) + c];
    }
    qb[(row << 5) + c] = (ushortT)f2bf(aq * C1F);   // q pre-scaled into log2 domain
    kb[(row << 5) + c] = (ushortT)f2bf(ak);
    vb[(row << 5) + c] = (ushortT)f2bf(av);
}

// ---------------------------------------------------------------- attention core (MFMA, 256-j chunk)
// 4 waves x 16 q-rows; chunk = 4 x 64-j subtiles, K/V^T/x double-buffered
// (one barrier per subtile). Per 32-j half per wave:
//   S^T = mfma(K-tile, Q^T) (2x) -> fp32 mask/dist2/online-softmax ->
//   P packed bf16 -> per-wave LDS transpose -> O^T += mfma(V^T-tile, P^T) (2x)
__global__ __launch_bounds__(256) void k_attn(const ushortT* __restrict__ qb,
                                              const ushortT* __restrict__ kb,
                                              const ushortT* __restrict__ vb,
                                              const float* __restrict__ xin,
                                              const unsigned long long* __restrict__ maskg,
                                              float* __restrict__ pm,
                                              float* __restrict__ ps,
                                              unsigned* __restrict__ pacc) {
    __shared__ __attribute__((aligned(16))) ushortT k_lds[2][64 * 32];    // 2x4KB
    __shared__ __attribute__((aligned(16))) ushortT vt_lds[2][32 * 72];   // 2x4.5KB
    __shared__ __attribute__((aligned(16))) float4  x_lds[2][64];         // 2x1KB
    __shared__ __attribute__((aligned(16))) ushortT p_lds[4][16 * 40];    // per-wave P^T, 5KB

    const int t = threadIdx.x;
    const int w = t >> 6, l = t & 63;
    const int g = l >> 4, q = l & 15;
    const int rowblk = blockIdx.x >> 3;      // 128 row-blocks of 64 rows
    const int cid    = blockIdx.x & 7;       // 8 chunks of 256 j
    const int bN = (rowblk >> 5) << 11;      // 32 row-blocks per batch
    const int j0 = cid << 8;
    const int rq = rowblk * 64 + w * 16 + q; // this lane's q-row

#define STAGE_TILE(BUF, TILE)                                                                  \
    do {                                                                                       \
        const int jj0 = (TILE) << 6;                                                           \
        __builtin_amdgcn_global_load_lds(                                                      \
            (const AS1 void*)((const char*)(kb + (((size_t)(bN + j0 + jj0)) << 5)) + t * 16),  \
            (AS3 void*)((char*)&k_lds[BUF][0] + t * 16), 16, 0, 0);                            \
        const int j_ = t & 63, grp_ = t >> 6;                                                  \
        const uint4 vv = *(const uint4*)(vb + (((size_t)(bN + j0 + jj0 + j_)) << 5) + grp_ * 8);\
        unsigned arr[4] = {vv.x, vv.y, vv.z, vv.w};                                            \
        _Pragma("unroll")                                                                      \
        for (int ii = 0; ii < 4; ++ii) {                                                       \
            vt_lds[BUF][(grp_ * 8 + 2 * ii) * 72 + j_]     = (ushortT)(arr[ii] & 0xffffu);     \
            vt_lds[BUF][(grp_ * 8 + 2 * ii + 1) * 72 + j_] = (ushortT)(arr[ii] >> 16);         \
        }                                                                                      \
        if (t < 64) {                                                                          \
            const float* xp_ = xin + ((size_t)(bN + j0 + jj0 + t)) * 3;                        \
            float4 xv_; xv_.x = xp_[0]; xv_.y = xp_[1]; xv_.z = xp_[2]; xv_.w = 0.f;           \
            x_lds[BUF][t] = xv_;                                                               \
        }                                                                                      \
    } while (0)

    // ---- per-lane state
    const v8s qf = *(const v8s*)(qb + (((size_t)rq) << 5) + g * 8);  // Q B-frag (row q, d=8g..)
    const float xi0 = xin[rq * 3 + 0], xi1 = xin[rq * 3 + 1], xi2 = xin[rq * 3 + 2];

    v4f oA = {0.f, 0.f, 0.f, 0.f}, oB = {0.f, 0.f, 0.f, 0.f};
    float m = NEGF, sum = 0.f;
    float xa0 = 0.f, xa1 = 0.f, xa2 = 0.f;

    ushortT* pw = &p_lds[w][0];

    STAGE_TILE(0, 0);
    __syncthreads();

    int cur = 0;
#pragma unroll
    for (int tile = 0; tile < 4; ++tile) {
        if (tile < 3) STAGE_TILE(cur ^ 1, tile + 1);
        const unsigned long long mw = maskg[(((size_t)rq) << 5) + (cid << 2) + tile];

#pragma unroll
        for (int half = 0; half < 2; ++half) {
            const int jt = half * 32;
            // --- QK^T: S^T tiles (j 0-15, 16-31 of this 32-block)
            v8s kA = *(const v8s*)(&k_lds[cur][0] + (jt + q) * 32 + g * 8);
            v8s kB = *(const v8s*)(&k_lds[cur][0] + (jt + 16 + q) * 32 + g * 8);
            v4f zero = {0.f, 0.f, 0.f, 0.f};
            v4f sA = __builtin_amdgcn_mfma_f32_16x16x32_bf16(kA, qf, zero, 0, 0, 0);
            v4f sB = __builtin_amdgcn_mfma_f32_16x16x32_bf16(kB, qf, zero, 0, 0, 0);

            // --- mask + dist2 + logits (fp32)
            float se[8];
            float4 xjA[4], xjB[4];
            float pot = NEGF;
#pragma unroll
            for (int reg = 0; reg < 4; ++reg) {
                const int jA = jt + 4 * g + reg, jB = jA + 16;
                xjA[reg] = x_lds[cur][jA];
                xjB[reg] = x_lds[cur][jB];
                float dA0 = xi0 - xjA[reg].x, dA1 = xi1 - xjA[reg].y, dA2 = xi2 - xjA[reg].z;
                float dB0 = xi0 - xjB[reg].x, dB1 = xi1 - xjB[reg].y, dB2 = xi2 - xjB[reg].z;
                float distA = fmaf(dA2, dA2, fmaf(dA1, dA1, dA0 * dA0));
                float distB = fmaf(dB2, dB2, fmaf(dB1, dB1, dB0 * dB0));
                const int bA = (int)((mw >> jA) & 1ULL);
                const int bB = (int)((mw >> jB) & 1ULL);
                se[reg]     = bA ? fmaf(distA, -LOG2E, sA[reg]) : NEGF;
                se[4 + reg] = bB ? fmaf(distB, -LOG2E, sB[reg]) : NEGF;
                pot = fmaxf(pot, fmaxf(se[reg], se[4 + reg]));
            }
            pot = fmaxf(pot, __shfl_xor(pot, 16));
            pot = fmaxf(pot, __shfl_xor(pot, 32));
            if (__any(pot - m > DEFER)) {
                float n2 = fmaxf(m, pot);
                float al = exp2_fast(m - n2);
                m = n2; sum *= al;
                v4f alv = {al, al, al, al};
                oA *= alv; oB *= alv;
                xa0 *= al; xa1 *= al; xa2 *= al;
            }
            float p[8];
#pragma unroll
            for (int i = 0; i < 8; ++i) { p[i] = exp2_fast(se[i] - m); sum += p[i]; }
#pragma unroll
            for (int reg = 0; reg < 4; ++reg) {
                xa0 = fmaf(p[reg], xjA[reg].x, fmaf(p[4 + reg], xjB[reg].x, xa0));
                xa1 = fmaf(p[reg], xjA[reg].y, fmaf(p[4 + reg], xjB[reg].y, xa1));
                xa2 = fmaf(p[reg], xjA[reg].z, fmaf(p[4 + reg], xjB[reg].z, xa2));
            }
            // --- pack P -> per-wave LDS [q][j-local], stride 40 shorts
            uint2 wA, wB;
            wA.x = f2bf(p[0]) | (f2bf(p[1]) << 16);
            wA.y = f2bf(p[2]) | (f2bf(p[3]) << 16);
            wB.x = f2bf(p[4]) | (f2bf(p[5]) << 16);
            wB.y = f2bf(p[6]) | (f2bf(p[7]) << 16);
            *(uint2*)(pw + q * 40 + 4 * g)      = wA;
            *(uint2*)(pw + q * 40 + 16 + 4 * g) = wB;
            // --- PV: O^T += V^T-tile * P^T
            v8s pf = *(const v8s*)(pw + q * 40 + 8 * g);
            v8s vA = *(const v8s*)(&vt_lds[cur][0] + q * 72 + jt + 8 * g);
            v8s vB = *(const v8s*)(&vt_lds[cur][0] + (16 + q) * 72 + jt + 8 * g);
            oA = __builtin_amdgcn_mfma_f32_16x16x32_bf16(vA, pf, oA, 0, 0, 0);
            oB = __builtin_amdgcn_mfma_f32_16x16x32_bf16(vB, pf, oB, 0, 0, 0);
        }
        __syncthreads();     // publishes next tile's staging; guards buffer reuse
        cur ^= 1;
    }
#undef STAGE_TILE

    // ---- reduce per-lane partials across the 4 groups of column q
    sum += __shfl_xor(sum, 16); sum += __shfl_xor(sum, 32);
    xa0 += __shfl_xor(xa0, 16); xa0 += __shfl_xor(xa0, 32);
    xa1 += __shfl_xor(xa1, 16); xa1 += __shfl_xor(xa1, 32);
    xa2 += __shfl_xor(xa2, 16); xa2 += __shfl_xor(xa2, 32);

    // ---- write partials
    unsigned* pb = pacc + ((size_t)cid * NRTOT + rq) * PREC;
    uint2 rA, rB;
    rA.x = f2bf(oA[0]) | (f2bf(oA[1]) << 16);
    rA.y = f2bf(oA[2]) | (f2bf(oA[3]) << 16);
    rB.x = f2bf(oB[0]) | (f2bf(oB[1]) << 16);
    rB.y = f2bf(oB[2]) | (f2bf(oB[3]) << 16);
    *(uint2*)(pb + 2 * g)     = rA;
    *(uint2*)(pb + 8 + 2 * g) = rB;
    if (g == 0) {
        float4 tl; tl.x = xa0; tl.y = xa1; tl.z = xa2; tl.w = 0.f;
        *(float4*)(pb + 16) = tl;
        pm[(((size_t)rq) << 3) + cid] = m;
        ps[(((size_t)rq) << 3) + cid] = sum;
    }
}

// ---------------------------------------------------------------- merge + epilogue + next-layer qkv
__global__ __launch_bounds__(256) void k_mergefin(const float* __restrict__ pm,
                                                  const float* __restrict__ ps,
                                                  const unsigned* __restrict__ pacc,
                                                  float* __restrict__ hg,
                                                  const float* __restrict__ xin,
                                                  float* __restrict__ xout,
                                                  const float* __restrict__ Wo,
                                                  const float* __restrict__ W1,
                                                  const float* __restrict__ W2,
                                                  const float* __restrict__ csp,
                                                  const float* __restrict__ Wqn,
                                                  const float* __restrict__ Wkn,
                                                  const float* __restrict__ Wvn,
                                                  ushortT* __restrict__ qout,
                                                  ushortT* __restrict__ kout,
                                                  ushortT* __restrict__ vout) {
    __shared__ float wo_s[1024];
    __shared__ float w1_s[2048];
    __shared__ float w2_s[2048];
    __shared__ float wq_s[1024];
    __shared__ float wk_s[1024];
    __shared__ float wv_s[1024];
    __shared__ float ad_s[4][40];
    __shared__ float h1_s[4][36];
    __shared__ float h2_s[4][36];
    __shared__ float f_s[4][64];

    const int t = threadIdx.x, w = t >> 6, lane = t & 63;
    for (int i = t; i < 1024; i += 256) wo_s[i] = Wo[i];
    for (int i = t; i < 2048; i += 256) { w1_s[i] = W1[i]; w2_s[i] = W2[i]; }
    if (Wqn) {
        for (int i = t; i < 1024; i += 256) {
            wq_s[i] = Wqn[i]; wk_s[i] = Wkn[i]; wv_s[i] = Wvn[i];
        }
    }
    __syncthreads();

    const int r = (blockIdx.x << 2) + w;

    // merge stats across 8 chunks ([r][8] layout)
    float pmv = NEGF, psv = 0.f;
    if (lane < NCHUNK) { pmv = pm[((size_t)r << 3) + lane]; psv = ps[((size_t)r << 3) + lane]; }
    float m_g = pmv;
#pragma unroll
    for (int off = 1; off < 64; off <<= 1) m_g = fmaxf(m_g, __shfl_xor(m_g, off));
    float scv = (lane < NCHUNK) ? exp2_fast(pmv - m_g) : 0.f;
    float sg = scv * psv;
#pragma unroll
    for (int off = 1; off < 64; off <<= 1) sg += __shfl_xor(sg, off);
    const float rinv = 1.0f / sg;

    // merged accumulator, lane = d. record: u32 j = dims 2j(lo),2j+1(hi); +fp32 tail
    const int off32 = (lane < 32) ? (lane >> 1) : (16 + ((lane - 32) & 3));
    const bool isTail = lane >= 32;
    const bool hiHalf = lane & 1;
    float ad = 0.f;
#pragma unroll
    for (int c = 0; c < NCHUNK; ++c) {
        float scc = __shfl(scv, c);
        unsigned u = pacc[((size_t)c * NRTOT + r) * PREC + off32];
        float f = isTail ? __builtin_bit_cast(float, u)
                         : __builtin_bit_cast(float, hiHalf ? (u & 0xffff0000u) : (u << 16));
        ad = fmaf(scc, f, ad);
    }
    if (lane < 35) ad_s[w][lane] = ad;

    // Wo matmul: lane&31 = col (both halves compute redundantly)
    const int col = lane & 31;
    float hv = 0.f;
#pragma unroll
    for (int d = 0; d < 32; ++d) hv = fmaf(ad_s[w][d], wo_s[(d << 5) + col], hv);
    float h1 = 0.f;
    if (lane < 32) { h1 = hg[(((size_t)r) << 5) + lane] + hv * rinv; h1_s[w][lane] = h1; }

    // FF up: lane = u (64)
    float f = 0.f;
#pragma unroll
    for (int d = 0; d < 32; ++d) f = fmaf(h1_s[w][d], w1_s[(d << 6) + lane], f);
    f = fmaxf(f, 0.f);
    f_s[w][lane] = f;

    // FF down + residual: lane<32 = col
    if (lane < 32) {
        float v2a = 0.f;
#pragma unroll
        for (int u = 0; u < 64; ++u) v2a = fmaf(f_s[w][u], w2_s[(u << 5) + lane], v2a);
        float hnew = h1 + v2a;
        hg[(((size_t)r) << 5) + lane] = hnew;
        h2_s[w][lane] = hnew;
    }

    // equivariant x update
    if (lane < 3) {
        float o  = ad_s[w][32 + lane] * rinv;
        float xi = xin[r * 3 + lane];
        xout[r * 3 + lane] = xi + csp[0] * (xi - o);
    }

    // fused next-layer qkv (lane<32 = output column), bf16 out
    if (Wqn && lane < 32) {
        float aq = 0.f, ak = 0.f, av = 0.f;
#pragma unroll
        for (int d = 0; d < 32; ++d) {
            float hd = h2_s[w][d];
            aq = fmaf(hd, wq_s[(d << 5) + lane], aq);
            ak = fmaf(hd, wk_s[(d << 5) + lane], ak);
            av = fmaf(hd, wv_s[(d << 5) + lane], av);
        }
        qout[(((size_t)r) << 5) + lane] = (ushortT)f2bf(aq * C1F);
        kout[(((size_t)r) << 5) + lane] = (ushortT)f2bf(ak);
        vout[(((size_t)r) << 5) + lane] = (ushortT)f2bf(av);
    }
}

// ---------------------------------------------------------------- pooling stage 1 (parallel)
__global__ __launch_bounds__(256) void k_pool(const float* __restrict__ h,
                                              float* __restrict__ pool_ws) {
    const int b = blockIdx.x >> 5, sub = blockIdx.x & 31;
    const int t = threadIdx.x, c = t & 31, g = t >> 5;
    float s = 0.f;
#pragma unroll
    for (int i = 0; i < 8; ++i) {
        int row = (sub << 6) + (g << 3) + i;
        s += h[(((size_t)((b << 11) + row)) << 5) + c];
    }
    __shared__ float pool[8][32];
    pool[g][c] = s;
    __syncthreads();
    if (t < 32) {
        float ss = 0.f;
#pragma unroll
        for (int gg = 0; gg < 8; ++gg) ss += pool[gg][t];
        pool_ws[((b << 5) + sub) * 32 + t] = ss;
    }
}

// ---------------------------------------------------------------- head (tiny)
__global__ __launch_bounds__(256) void k_head(const float* __restrict__ pool_ws,
                                              const float* __restrict__ Wf1,
                                              const float* __restrict__ bf1,
                                              const float* __restrict__ Wf2,
                                              const float* __restrict__ bf2,
                                              float* __restrict__ out) {
    __shared__ float pooled[4][32];
    __shared__ float a1[4][16];
    const int t = threadIdx.x;
    if (t < 128) {
        int b = t >> 5, c = t & 31;
        float ss = 0.f;
#pragma unroll
        for (int sub = 0; sub < 32; ++sub) ss += pool_ws[((b << 5) + sub) * 32 + c];
        pooled[b][c] = ss * (1.0f / N_);
    }
    __syncthreads();
    if (t < 64) {
        int b = t >> 4, u = t & 15;
        float a = bf1[u];
#pragma unroll
        for (int d = 0; d < 32; ++d) a += pooled[b][d] * Wf1[(d << 4) + u];
        a1[b][u] = fmaxf(a, 0.f);
    }
    __syncthreads();
    if (t < 12) {
        int b = t / 3, o = t - b * 3;
        float v = bf2[o];
#pragma unroll
        for (int e = 0; e < 16; ++e) v += a1[b][e] * Wf2[e * 3 + o];
        out[b * 3 + o] = v;
    }
}

// ---------------------------------------------------------------- launch
extern "C" void kernel_launch(void* const* d_in, const int* in_sizes, int n_in,
                              void* d_out, int out_size, void* d_ws, size_t ws_size,
                              hipStream_t stream) {
    const float* feats = (const float*)d_in[0];
    const float* coors = (const float*)d_in[1];
    const int*   adj   = (const int*)d_in[2];
    const float* W_in  = (const float*)d_in[3];
    const float* Wq    = (const float*)d_in[4];
    const float* Wk    = (const float*)d_in[5];
    const float* Wv    = (const float*)d_in[6];
    const float* Wo    = (const float*)d_in[7];
    const float* W1    = (const float*)d_in[8];
    const float* W2    = (const float*)d_in[9];
    const float* csc   = (const float*)d_in[10];
    const float* Wf1   = (const float*)d_in[11];
    const float* bf1   = (const float*)d_in[12];
    const float* Wf2   = (const float*)d_in[13];
    const float* bf2   = (const float*)d_in[14];

    const size_t BNH = (size_t)4 * N_ * H_;   // 262144
    float* ws = (float*)d_ws;
    float* h  = ws;
    ushortT* qb = (ushortT*)(ws + BNH);       // BNH ushorts each (512KB)
    ushortT* kb = qb + BNH;
    ushortT* vb = kb + BNH;
    float* x0 = (float*)(vb + BNH);           // 24576 floats
    float* x1 = x0 + (size_t)4 * N_ * 3;
    unsigned long long* mask = (unsigned long long*)(x1 + (size_t)4 * N_ * 3);  // 262144 u64
    float* pm   = (float*)(mask + 262144);    // 8*8192 floats
    float* ps   = pm + (size_t)NCHUNK * NRTOT;
    unsigned* pacc = (unsigned*)(ps + (size_t)NCHUNK * NRTOT);  // 8*8192*20 u32 (5.2MB)
    float* pool_ws = (float*)(pacc + (size_t)NCHUNK * NRTOT * PREC);  // 4096 floats

    k_adjmask<<<65536, 256, 0, stream>>>(adj, mask);
    k_init_qkv<<<1024, 256, 0, stream>>>(feats, W_in, Wq, Wk, Wv, h, qb, kb, vb);

    const float* xin[3]  = {coors, x0, x1};
    float*       xout[3] = {x0, x1, x0};
    for (int l = 0; l < 3; ++l) {
        k_attn<<<1024, 256, 0, stream>>>(qb, kb, vb, xin[l], mask, pm, ps, pacc);
        const bool last = (l == 2);
        k_mergefin<<<2048, 256, 0, stream>>>(pm, ps, pacc, h, xin[l], xout[l],
                                             Wo + l * 1024, W1 + l * 2048, W2 + l * 2048,
                                             csc + l,
                                             last ? nullptr : Wq + (l + 1) * 1024,
                                             last ? nullptr : Wk + (l + 1) * 1024,
                                             last ? nullptr : Wv + (l + 1) * 1024,
                                             qb, kb, vb);
    }
    k_pool<<<128, 256, 0, stream>>>(h, pool_ws);
    k_head<<<1, 256, 0, stream>>>(pool_ws, Wf1, bf1, Wf2, bf2, (float*)d_out);
}